// Round 4
// baseline (297.887 us; speedup 1.0000x reference)
//
#include <hip/hip_runtime.h>
#include <hip/hip_bf16.h>
#include <string.h>

// CrossOp via bf16 MFMA implicit-GEMM, w-split for occupancy.
// Block = (b, h, w-half): 1 output row x 64 px x all 64 co. Grid 1024 = 4 blocks/CU.
// 4 waves; wave w owns co 16w..16w+15. K = shift*16+ci, padded 144->160.
// LDS: [3 rows][66 cols][16 ci pad 24] bf16, double-buffered (19 KB).
// XCD swizzle: xcd = bid&7 -> (b, w-half); h = bid>>3 -> halo rows L2-local.

typedef __attribute__((ext_vector_type(8))) short short8;
typedef __attribute__((ext_vector_type(4))) float f32x4;
typedef __attribute__((ext_vector_type(4))) unsigned int u32x4;

#define NEG_SLOPE 0.01f

constexpr int CIP      = 24;             // ci pitch in shorts (48 B)
constexpr int COLS     = 66;             // 64 + 2 halo
constexpr int ROWPITCH = COLS * CIP;     // 1584 shorts
constexpr int BUFSH    = 3 * ROWPITCH;   // 4752 shorts = 9504 B

__device__ __forceinline__ short to_bf16s(float f) {
    unsigned u = __builtin_bit_cast(unsigned, f);
    u += 0x7fffu + ((u >> 16) & 1u);     // RNE
    return (short)(u >> 16);
}

__device__ __forceinline__ unsigned pack2(float a, float b) {
    __hip_bfloat162 h = __float22bfloat162_rn(float2{a, b});   // v_cvt_pk_bf16_f32
    unsigned u;
    memcpy(&u, &h, sizeof(u));
    return u;
}

__global__ __launch_bounds__(256, 4)
void crossop_mfma(const float* __restrict__ xp, const float* __restrict__ yp,
                  const float* __restrict__ wp, const float* __restrict__ bp,
                  float* __restrict__ out)
{
    __shared__ __align__(16) short st[2][BUFSH];

    const int bid = blockIdx.x;            // 0..1023
    const int xcd = bid & 7;               // -> (b, w-half), fixed per XCD
    const int h   = bid >> 3;              // 0..127
    const int b   = xcd >> 1;
    const int w0  = (xcd & 1) << 6;

    const int tid  = threadIdx.x;
    const int lane = tid & 63;
    const int wid  = tid >> 6;
    const int q    = lane >> 4;            // quadrant 0..3
    const int mm   = lane & 15;
    const int co0  = wid << 4;

    // staging thread mapping
    const int  ch   = tid >> 7;            // ci half
    const int  wv   = tid & 127;           // LDS col; active if < COLS
    const bool sact = wv < COLS;
    const int  scol = w0 - 1 + wv;         // input col
    const bool scv  = sact && (unsigned)scol < 128u;

    float* ntgt  = out;
    float* inter = out + (size_t)4 * 64 * 16384;

    float sr[3][8];                        // in-flight staged values

#define STAGE_ISSUE(SRC) do {                                                 \
    const float* _s = (SRC);                                                  \
    _Pragma("unroll")                                                         \
    for (int it = 0; it < 3; ++it) {                                          \
        int hh = h + it - 1;                                                  \
        bool v = scv && (unsigned)hh < 128u;                                  \
        const float* p = _s + (ptrdiff_t)(ch * 8) * 16384                     \
                            + (ptrdiff_t)hh * 128 + scol;                     \
        _Pragma("unroll")                                                     \
        for (int c = 0; c < 8; ++c)                                           \
            sr[it][c] = v ? p[(ptrdiff_t)c * 16384] : 0.f;                    \
    } } while (0)

#define STAGE_WRITE(BUF) do { if (sact) {                                     \
    _Pragma("unroll")                                                         \
    for (int it = 0; it < 3; ++it) {                                          \
        u32x4 vv;                                                             \
        _Pragma("unroll")                                                     \
        for (int c2 = 0; c2 < 4; ++c2)                                        \
            vv[c2] = pack2(sr[it][2 * c2], sr[it][2 * c2 + 1]);               \
        *(u32x4*)&(BUF)[it * ROWPITCH + wv * CIP + ch * 8] = vv;              \
    } } } while (0)

    // ---------------- weight fragments + B-frag offsets -------------------
    short8 wx[5], wy[5];
    {
        const int co_a = co0 + mm;
        #pragma unroll
        for (int f = 0; f < 5; ++f) {
            #pragma unroll
            for (int j = 0; j < 8; ++j) {
                int k = f * 32 + q * 8 + j;
                short vx = 0, vy = 0;
                if (k < 144) {
                    int sh = k >> 4, ci = k & 15;
                    vx = to_bf16s(wp[(co_a * 32 + ci) * 9 + sh]);
                    vy = to_bf16s(wp[(co_a * 32 + 16 + ci) * 9 + sh]);
                }
                wx[f][j] = vx;
                wy[f][j] = vy;
            }
        }
    }
    int Pf[5];
    #pragma unroll
    for (int f = 0; f < 5; ++f) {
        int sh = 2 * f + (q >> 1);
        if (sh > 8) sh = 8;                // pad-k: weights 0, value dont-care
        int kh = sh / 3, kw = sh - kh * 3;
        Pf[f] = kh * ROWPITCH + (kw + mm) * CIP + ((q & 1) << 3);
    }
    float bias4[4];
    #pragma unroll
    for (int r = 0; r < 4; ++r) bias4[r] = bp[co0 + q * 4 + r];

    // ---------------- prologue: x -> buf0, ox; y0 -> buf1 ------------------
    STAGE_ISSUE(xp + (size_t)b * 16 * 16384);
    STAGE_WRITE(st[0]);
    __syncthreads();

    float ox[4][4];
    {
        const short* sb = st[0];
        #pragma unroll
        for (int t = 0; t < 4; ++t) {
            f32x4 acc = {bias4[0], bias4[1], bias4[2], bias4[3]};
            #pragma unroll
            for (int f = 0; f < 5; ++f) {
                short8 bb = *(const short8*)&sb[Pf[f] + t * 384];
                acc = __builtin_amdgcn_mfma_f32_16x16x32_bf16(wx[f], bb, acc, 0, 0, 0);
            }
            #pragma unroll
            for (int r = 0; r < 4; ++r) ox[t][r] = acc[r];
        }
    }

    STAGE_ISSUE(yp + (size_t)(b * 32) * 16 * 16384);
    STAGE_WRITE(st[1]);
    __syncthreads();

    // ---------------- s-loop ----------------------------------------------
    float msum[4][4];
    #pragma unroll
    for (int t = 0; t < 4; ++t)
        #pragma unroll
        for (int r = 0; r < 4; ++r) msum[t][r] = 0.f;

    for (int s = 0; s < 32; ++s) {
        const int rbuf = (s + 1) & 1;
        const int wbuf = s & 1;
        const bool pf = (s < 31);

        if (pf) STAGE_ISSUE(yp + (size_t)(b * 32 + s + 1) * 16 * 16384);

        {
            const short* sb = st[rbuf];
            float* ibase = inter + ((size_t)(b * 32 + s) * 64 + co0 + q * 4) * 16384
                         + (size_t)h * 128 + w0;
            #pragma unroll
            for (int t = 0; t < 4; ++t) {
                f32x4 acc = {ox[t][0], ox[t][1], ox[t][2], ox[t][3]};
                #pragma unroll
                for (int f = 0; f < 5; ++f) {
                    short8 bb = *(const short8*)&sb[Pf[f] + t * 384];
                    acc = __builtin_amdgcn_mfma_f32_16x16x32_bf16(wy[f], bb, acc, 0, 0, 0);
                }
                #pragma unroll
                for (int r = 0; r < 4; ++r) {
                    float v = acc[r];
                    v = v >= 0.f ? v : NEG_SLOPE * v;
                    __builtin_nontemporal_store(v, ibase + (size_t)r * 16384 + t * 16 + mm);
                    msum[t][r] += v;
                }
            }
        }

        if (pf) STAGE_WRITE(st[wbuf]);
        __syncthreads();
    }

    // ---------------- mean over Sy ----------------------------------------
    {
        float* nb = ntgt + ((size_t)b * 64 + co0 + q * 4) * 16384
                  + (size_t)h * 128 + w0;
        #pragma unroll
        for (int t = 0; t < 4; ++t)
            #pragma unroll
            for (int r = 0; r < 4; ++r)
                __builtin_nontemporal_store(msum[t][r] * 0.03125f,
                                            nb + (size_t)r * 16384 + t * 16 + mm);
    }
#undef STAGE_ISSUE
#undef STAGE_WRITE
}

extern "C" void kernel_launch(void* const* d_in, const int* in_sizes, int n_in,
                              void* d_out, int out_size, void* d_ws, size_t ws_size,
                              hipStream_t stream) {
    const float* x    = (const float*)d_in[0];
    const float* y    = (const float*)d_in[1];
    const float* wgt  = (const float*)d_in[2];
    const float* bias = (const float*)d_in[3];
    float* out = (float*)d_out;

    crossop_mfma<<<1024, 256, 0, stream>>>(x, y, wgt, bias, out);
}

// Round 5
// 178.549 us; speedup vs baseline: 1.6684x; 1.6684x over previous
//
#include <hip/hip_runtime.h>
#include <hip/hip_bf16.h>
#include <string.h>

// CrossOp via bf16 MFMA (32x32x16) implicit-GEMM.
// Block = (b, h): one output row, 128 px, all 64 co. Grid 512, 4 waves.
// Wave w: co-half (w&1)*32, px-groups (w>>1)*32 and (w>>1)*32+64 (32 px each).
// K = shift*16 + ci; 9 MFMA k-steps of 16 (one 3x3 shift each), no padding.
// LDS: [3 rows][130 cols][16 ci pad->24] bf16, double-buffered (37.4 KB).
// 32x32 C-layout => stores are 2 full 128B lines/instr (no write amplification).

typedef __attribute__((ext_vector_type(8))) short short8;
typedef __attribute__((ext_vector_type(16))) float f32x16;
typedef __attribute__((ext_vector_type(4))) unsigned int u32x4;

#define NEG_SLOPE 0.01f

constexpr int CIP   = 24;              // shorts per (row,col) ci slab (48 B)
constexpr int COLS  = 130;             // 128 + 2 halo
constexpr int ROWP  = COLS * CIP;      // 3120 shorts
constexpr int BUFSH = 3 * ROWP;        // 9360 shorts = 18.7 KB per buffer

__device__ __forceinline__ short to_bf16s(float f) {
    unsigned u = __builtin_bit_cast(unsigned, f);
    u += 0x7fffu + ((u >> 16) & 1u);   // RNE
    return (short)(u >> 16);
}

__device__ __forceinline__ unsigned pack2(float a, float b) {
    __hip_bfloat162 t = __float22bfloat162_rn(float2{a, b});   // v_cvt_pk_bf16_f32
    unsigned u;
    memcpy(&u, &t, sizeof(u));
    return u;
}

__global__ __launch_bounds__(256, 2)
void crossop_mfma32(const float* __restrict__ xp, const float* __restrict__ yp,
                    const float* __restrict__ wp, const float* __restrict__ bp,
                    float* __restrict__ out)
{
    __shared__ __align__(16) short st[2][BUFSH];

    const int bid     = blockIdx.x;                     // 0..511
    const int logical = ((bid & 7) << 6) | (bid >> 3);  // XCD-chunked swizzle
    const int b       = logical >> 7;
    const int h       = logical & 127;

    const int tid  = threadIdx.x;
    const int lane = tid & 63;
    const int wid  = tid >> 6;
    const int l31  = lane & 31;
    const int hi   = lane >> 5;            // k-half / +4 co rows
    const int co0w = (wid & 1) << 5;       // wave's co base (0 or 32)
    const int pxg0 = wid >> 1;             // wave's first px-group (0 or 1)

    float* ntgt  = out;
    float* inter = out + (size_t)4 * 64 * 16384;

    // ---------------- zero LDS once (halo cols 0,129 + OOB rows stay 0) ---
    {
        u32x4 zz = {0, 0, 0, 0};
        u32x4* z = (u32x4*)&st[0][0];
        for (int i = tid; i < (2 * BUFSH * 2) / 16; i += 256) z[i] = zz;
    }

    // ---------------- staging mapping: all 256 threads active -------------
    const int ch = tid >> 7;               // ci half
    const int wv = tid & 127;              // input col w = wv, LDS col wv+1
    float sr[3][8];

#define STAGE_ISSUE(SRC) do {                                                 \
    const float* _s = (SRC);                                                  \
    _Pragma("unroll")                                                         \
    for (int it = 0; it < 3; ++it) {                                          \
        int hh = h + it - 1;                                                  \
        bool v = (unsigned)hh < 128u;                                         \
        const float* p = _s + (ptrdiff_t)(ch * 8) * 16384                     \
                            + (ptrdiff_t)hh * 128 + wv;                       \
        _Pragma("unroll")                                                     \
        for (int c = 0; c < 8; ++c)                                           \
            sr[it][c] = v ? p[(ptrdiff_t)c * 16384] : 0.f;                    \
    } } while (0)

#define STAGE_WRITE(BUF) do {                                                 \
    _Pragma("unroll")                                                         \
    for (int it = 0; it < 3; ++it) {                                          \
        if ((unsigned)(h + it - 1) < 128u) {                                  \
            u32x4 vv;                                                         \
            _Pragma("unroll")                                                 \
            for (int c2 = 0; c2 < 4; ++c2)                                    \
                vv[c2] = pack2(sr[it][2 * c2], sr[it][2 * c2 + 1]);           \
            *(u32x4*)&(BUF)[it * ROWP + (wv + 1) * CIP + ch * 8] = vv;        \
        }                                                                     \
    } } while (0)

    // ---------------- persistent wy fragments (9 x short8 = 36 VGPR) ------
    short8 wy[9];
    #pragma unroll
    for (int sh = 0; sh < 9; ++sh) {
        #pragma unroll
        for (int j = 0; j < 8; ++j) {
            int ci = hi * 8 + j;           // k = (lane>>5)*8 + j within k-step
            wy[sh][j] = to_bf16s(wp[((co0w + l31) * 32 + 16 + ci) * 9 + sh]);
        }
    }

    // per-lane B column bases (shorts) for the two px groups
    const int cb0 = (pxg0 * 32 + l31) * CIP + hi * 8;
    const int cb1 = (pxg0 * 32 + 64 + l31) * CIP + hi * 8;

    // ---------------- prologue: x -> buf0; ox = conv_x + bias -------------
    STAGE_ISSUE(xp + (size_t)b * 16 * 16384);
    STAGE_WRITE(st[0]);
    __syncthreads();

    f32x16 ox0, ox1;
    #pragma unroll
    for (int r = 0; r < 16; ++r) {
        float bv = bp[co0w + (r & 3) + 8 * (r >> 2) + 4 * hi];
        ox0[r] = bv; ox1[r] = bv;
    }
    {
        const short* sb = st[0];
        #pragma unroll
        for (int sh = 0; sh < 9; ++sh) {
            short8 ax;
            #pragma unroll
            for (int j = 0; j < 8; ++j) {
                int ci = hi * 8 + j;
                ax[j] = to_bf16s(wp[((co0w + l31) * 32 + ci) * 9 + sh]);
            }
            const int off = (sh / 3) * ROWP + (sh % 3) * CIP;
            ox0 = __builtin_amdgcn_mfma_f32_32x32x16_bf16(ax, *(const short8*)&sb[cb0 + off], ox0, 0, 0, 0);
            ox1 = __builtin_amdgcn_mfma_f32_32x32x16_bf16(ax, *(const short8*)&sb[cb1 + off], ox1, 0, 0, 0);
        }
    }

    STAGE_ISSUE(yp + (size_t)(b * 32) * 16 * 16384);
    STAGE_WRITE(st[1]);
    __syncthreads();

    // ---------------- s-loop ----------------------------------------------
    f32x16 ms0, ms1;
    #pragma unroll
    for (int r = 0; r < 16; ++r) { ms0[r] = 0.f; ms1[r] = 0.f; }

    for (int s = 0; s < 32; ++s) {
        const short* sb = st[(s + 1) & 1];
        const bool pf = (s < 31);

        if (pf) STAGE_ISSUE(yp + (size_t)(b * 32 + s + 1) * 16 * 16384);

        const size_t sbase = ((size_t)(b * 32 + s) * 64 + co0w + 4 * hi) * 16384
                           + (size_t)h * 128;

        // px group 0
        {
            f32x16 acc = ox0;
            #pragma unroll
            for (int sh = 0; sh < 9; ++sh) {
                const int off = (sh / 3) * ROWP + (sh % 3) * CIP;
                acc = __builtin_amdgcn_mfma_f32_32x32x16_bf16(wy[sh], *(const short8*)&sb[cb0 + off], acc, 0, 0, 0);
            }
            float* p0 = inter + sbase + pxg0 * 32 + l31;
            #pragma unroll
            for (int r = 0; r < 16; ++r) {
                float v = acc[r];
                v = v >= 0.f ? v : NEG_SLOPE * v;
                __builtin_nontemporal_store(v, p0 + (ptrdiff_t)((r & 3) + 8 * (r >> 2)) * 16384);
                ms0[r] += v;
            }
        }
        // px group 1
        {
            f32x16 acc = ox1;
            #pragma unroll
            for (int sh = 0; sh < 9; ++sh) {
                const int off = (sh / 3) * ROWP + (sh % 3) * CIP;
                acc = __builtin_amdgcn_mfma_f32_32x32x16_bf16(wy[sh], *(const short8*)&sb[cb1 + off], acc, 0, 0, 0);
            }
            float* p1 = inter + sbase + pxg0 * 32 + 64 + l31;
            #pragma unroll
            for (int r = 0; r < 16; ++r) {
                float v = acc[r];
                v = v >= 0.f ? v : NEG_SLOPE * v;
                __builtin_nontemporal_store(v, p1 + (ptrdiff_t)((r & 3) + 8 * (r >> 2)) * 16384);
                ms1[r] += v;
            }
        }

        if (pf) STAGE_WRITE(st[s & 1]);
        __syncthreads();
    }

    // ---------------- mean over Sy ----------------------------------------
    {
        const size_t nb = ((size_t)b * 64 + co0w + 4 * hi) * 16384 + (size_t)h * 128;
        float* p0 = ntgt + nb + pxg0 * 32 + l31;
        float* p1 = ntgt + nb + pxg0 * 32 + 64 + l31;
        #pragma unroll
        for (int r = 0; r < 16; ++r) {
            const ptrdiff_t off = (ptrdiff_t)((r & 3) + 8 * (r >> 2)) * 16384;
            __builtin_nontemporal_store(ms0[r] * 0.03125f, p0 + off);
            __builtin_nontemporal_store(ms1[r] * 0.03125f, p1 + off);
        }
    }
#undef STAGE_ISSUE
#undef STAGE_WRITE
}

extern "C" void kernel_launch(void* const* d_in, const int* in_sizes, int n_in,
                              void* d_out, int out_size, void* d_ws, size_t ws_size,
                              hipStream_t stream) {
    const float* x    = (const float*)d_in[0];
    const float* y    = (const float*)d_in[1];
    const float* wgt  = (const float*)d_in[2];
    const float* bias = (const float*)d_in[3];
    float* out = (float*)d_out;

    crossop_mfma32<<<512, 256, 0, stream>>>(x, y, wgt, bias, out);
}